// Round 12
// baseline (170.785 us; speedup 1.0000x reference)
//
#include <hip/hip_runtime.h>
#include <math.h>

#define DEPTH   5
#define HIDDEN  128
#define CODE    400
#define NFREQ   9
#define BATCH   8
#define NPTS    262144
#define PTSB    64
#define BLOCK   256

typedef __attribute__((ext_vector_type(8))) short sh8;
typedef __attribute__((ext_vector_type(4))) float f32x4;
typedef __attribute__((ext_vector_type(4))) uint  u32x4;
typedef __attribute__((ext_vector_type(2))) uint  u32x2;

struct CoefTab { float c[54]; };   // [s][yk] SH normalization, host-computed

__device__ __forceinline__ ushort f2bf(float f) {   // round-to-nearest-even
    union { float f; uint u; } v; v.f = f;
    uint r = v.u + 0x7fffu + ((v.u >> 16) & 1u);
    return (ushort)(r >> 16);
}

// ---------------------------------------------------------------------------
// Prep (identical to R6/R10 proven version). gwB = single rounded bf16 Wfwd.
// ---------------------------------------------------------------------------
__global__ void sinr_prep(const float* __restrict__ a,
                          const float* __restrict__ Wcode,
                          const float* __restrict__ bcode,
                          const float* __restrict__ bfwd,
                          const float* __restrict__ Wftr,
                          const float* __restrict__ bftr,
                          const float* __restrict__ Wfwd,
                          CoefTab ct,
                          float* __restrict__ cterm,
                          ushort* __restrict__ wfB,
                          ushort* __restrict__ gwB) {
    int blk = blockIdx.x, tid = threadIdx.x;
    if (blk < DEPTH * BATCH) {
        if (tid < HIDDEN) {
            int i = blk / BATCH, b = blk % BATCH, h = tid;
            const float* ar = a + b * CODE;
            const float* wr = Wcode + (i * HIDDEN + h) * CODE;
            float acc = bcode[i * HIDDEN + h] + bfwd[i * HIDDEN + h];
            for (int c = 0; c < CODE; c += 4) {
                float4 av = *(const float4*)(ar + c);
                float4 wv = *(const float4*)(wr + c);
                acc = fmaf(av.x, wv.x, acc);
                acc = fmaf(av.y, wv.y, acc);
                acc = fmaf(av.z, wv.z, acc);
                acc = fmaf(av.w, wv.w, acc);
            }
            cterm[(i * BATCH + b) * HIDDEN + h] = acc;
        }
    } else if (blk < DEPTH * BATCH + 192) {
        int e = (blk - DEPTH * BATCH) * BLOCK + tid;     // < 49152
        int j    = e & 7;
        int lane = (e >> 3) & 63;
        int t    = (e >> 9) & 1;
        int nt   = (e >> 10) & 7;
        int s    = e >> 13;                               // 0..5
        int g  = nt * 16 + (lane & 15);
        int kq = lane >> 4;
        float v = 0.0f;
        if (kq == 0 || kq == 2) {
            v = ct.c[s * 9 + j] * Wftr[(s * HIDDEN + g) * NFREQ + j];
        } else if (kq == 1) {
            if (j == 0 || j == 1)
                v = ct.c[s * 9 + 8] * Wftr[(s * HIDDEN + g) * NFREQ + 8];
            else if (j == 2)
                v = bftr[s * HIDDEN + g];
        }
        uint u = __float_as_uint(v);
        float rf = v - __uint_as_float(u & 0xFFFF0000u);
        wfB[e] = t ? f2bf(rf) : (ushort)(u >> 16);
    } else {
        int e = (blk - DEPTH * BATCH - 192) * BLOCK + tid;  // < 81920
        if (e < DEPTH * 4 * 8 * 512) {
            int j     = e & 7;
            int lane  = (e >> 3) & 63;
            int nt    = (e >> 9) & 7;
            int kq    = (e >> 12) & 3;
            int layer = e >> 14;
            int g = nt * 16 + (lane & 15);
            int h = kq * 32 + (lane >> 4) * 8 + j;
            gwB[e] = f2bf(Wfwd[(layer * HIDDEN + g) * HIDDEN + h]);
        }
    }
}

// ---------------------------------------------------------------------------
// Main. vs R11 (91.9 us proven): three independent cheap levers, structure
// untouched (swapped-MFMA transposed fragments, ypk dbuf, unroll-1 kq loop):
//  * __launch_bounds__(256, 6): reg cap 85 >= current 64 use (no-spill,
//    unlike R3/R8 where usage exceeded cap). LDS 22.5 KB allows 7 blocks ->
//    6 blocks/CU resident, +50% TLP to hide barriers + store conflicts.
//  * zstore4 via v_cvt_pk_bf16_f32 (HW RNE == f2bf's RNE for all normals):
//    ~14 -> 2 VALU per 4-elem store, ~550 ops/thread off the hot VALU path.
//  * Legendre recurrence: divide by (l-am)=s (compile-time const) -> multiply
//    by folded reciprocal. s=2,4 exact; s=3,5 <=1 ulp f32 on P, invisible
//    after bf16 truncation (error margin 0.00195 vs 0.02). Kills 20 divide
//    sequences (~180 VALU ops).
// ---------------------------------------------------------------------------
__global__ __launch_bounds__(BLOCK, 6)
void sinr_main(const float* __restrict__ x,
               const ushort* __restrict__ wfB,
               const ushort* __restrict__ gwB,
               const float* __restrict__ cterm,
               const float* __restrict__ Wout,
               const float* __restrict__ boutp,
               float* __restrict__ out,
               float* __restrict__ out_x) {
    __shared__ __align__(16) ushort zh16[PTSB * HIDDEN];     // 16 KB
    __shared__ __align__(16) ushort ypk[2 * 3 * PTSB * 8];   // 6 KB (dbuf)
    __shared__ __align__(16) ushort zrow[8];

    const int tid  = threadIdx.x;
    const int lane = tid & 63;
    const int w    = tid >> 6;
    const int l15  = lane & 15, lq = lane >> 4;
    const int p0   = blockIdx.x * PTSB;
    const int b    = p0 >> 15;

    if (tid < 2 * PTSB) out_x[p0 * 2 + tid] = x[p0 * 2 + tid];
    if (tid < 8) zrow[tid] = 0;

    // staged pre-packed shift (wave w owns shift: w==0->4, 1->5, 2->2, 3->3)
    sh8 pk0, pk2;
    uint pk1w = 0;   // k1[0] | k1[1]<<16 (rest of k1 is constant)

    // store one packed shift triple into ypk buffer `buf`
    auto ystore = [&](int buf, const sh8& k0, const sh8& k1, const sh8& k2) {
        int off = (buf * 3 * PTSB + lane) * 8;
        *(sh8*)&ypk[off]                = k0;
        *(sh8*)&ypk[off + PTSB * 8]     = k1;
        *(sh8*)&ypk[off + 2 * PTSB * 8] = k2;
    };

    // ---- harmonics: every wave computes the full proven P/trig table ------
    {
        float th = x[(p0 + lane) * 2 + 0];
        float ph = x[(p0 + lane) * 2 + 1];
        float c  = cosf(ph);
        float somx2 = sqrtf(fmaxf(1.0f - c * c, 0.0f));
        float s1, c1;
        sincosf(th, &s1, &c1);
        float ctab[5], stab[5];
        ctab[0] = 1.0f; stab[0] = 0.0f;
        ctab[1] = c1;   stab[1] = s1;
#pragma unroll
        for (int k = 2; k <= 4; ++k) {
            ctab[k] = ctab[k - 1] * c1 - stab[k - 1] * s1;
            stab[k] = stab[k - 1] * c1 + ctab[k - 1] * s1;
        }
        float P[5][6];
        float pmm = 1.0f;
#pragma unroll
        for (int am = 0; am <= 4; ++am) {
            if (am > 0) pmm *= -(2.0f * am - 1.0f) * somx2;
            float pm2 = pmm;
            float pm1 = c * (2.0f * am + 1.0f) * pmm;
            P[am][0] = pm2;
            P[am][1] = pm1;
#pragma unroll
            for (int s = 2; s < 6; ++s) {
                int l = am + s;
                // divisor (l-am) == s is an unroll-time constant: multiply by
                // the folded reciprocal (s=2,4 exact; s=3,5 <=1 ulp on P).
                float pl = ((2.0f * l - 1.0f) * c * pm1
                            - (float)(l + am - 1) * pm2) * (1.0f / (float)s);
                P[am][s] = pl;
                pm2 = pm1;
                pm1 = pl;
            }
        }
        // verbatim proven pack loop, parameterized by the 5 P values
        auto mk = [&](float Pv0, float Pv1, float Pv2, float Pv3, float Pv4,
                      sh8& k0, sh8& k1, sh8& k2) {
            float Pv[5] = {Pv0, Pv1, Pv2, Pv3, Pv4};
            ushort yh[9], yl[9];
#pragma unroll
            for (int mm = -4; mm <= 4; ++mm) {
                int am = mm < 0 ? -mm : mm;
                float trig = (mm > 0) ? ctab[am] : ((mm < 0) ? stab[am] : 1.0f);
                float yv = Pv[am] * trig;
                uint u = __float_as_uint(yv);
                yh[mm + 4] = (ushort)(u >> 16);
                float rf = yv - __uint_as_float(u & 0xFFFF0000u);
                yl[mm + 4] = (ushort)(__float_as_uint(rf) >> 16);
            }
#pragma unroll
            for (int j = 0; j < 8; ++j) { k0[j] = (short)yh[j]; k2[j] = (short)yl[j]; }
            k1[0] = (short)yh[8]; k1[1] = (short)yl[8]; k1[2] = (short)0x3F80;
            k1[3] = 0; k1[4] = 0; k1[5] = 0; k1[6] = 0; k1[7] = 0;
        };
        sh8 t0, t1, t2;
        if (w == 0) {
            mk(P[0][0], P[1][0], P[2][0], P[3][0], P[4][0], t0, t1, t2);
            ystore(0, t0, t1, t2);
            mk(P[0][4], P[1][4], P[2][4], P[3][4], P[4][4], pk0, t1, pk2);
            pk1w = (uint)(ushort)t1[0] | ((uint)(ushort)t1[1] << 16);
        } else if (w == 1) {
            mk(P[0][1], P[1][1], P[2][1], P[3][1], P[4][1], t0, t1, t2);
            ystore(1, t0, t1, t2);
            mk(P[0][5], P[1][5], P[2][5], P[3][5], P[4][5], pk0, t1, pk2);
            pk1w = (uint)(ushort)t1[0] | ((uint)(ushort)t1[1] << 16);
        } else if (w == 2) {
            mk(P[0][2], P[1][2], P[2][2], P[3][2], P[4][2], pk0, t1, pk2);
            pk1w = (uint)(ushort)t1[0] | ((uint)(ushort)t1[1] << 16);
        } else {
            mk(P[0][3], P[1][3], P[2][3], P[3][3], P[4][3], pk0, t1, pk2);
            pk1w = (uint)(ushort)t1[0] | ((uint)(ushort)t1[1] << 16);
        }
    }
    __syncthreads();

    // z store, TRANSPOSED fragment: lane holds point row = mt*16+l15 and 4
    // consecutive h = (w*2+nt)*16 + lq*4 + r; one b64 write per (mt,nt).
    // Conversion via HW v_cvt_pk_bf16_f32 (RNE, matches f2bf on normals).
    auto zstore4 = [&](int mt, int nt, f32x4 t) {
        int row = mt * 16 + l15;
        int ch  = (w * 2 + nt) * 2 + (lq >> 1);
        int idx = row * HIDDEN + ((ch ^ l15) << 3) + (lq & 1) * 4;
        u32x2 pv;
        asm("v_cvt_pk_bf16_f32 %0, %1, %2" : "=v"(pv.x) : "v"(t[0]), "v"(t[1]));
        asm("v_cvt_pk_bf16_f32 %0, %1, %2" : "=v"(pv.y) : "v"(t[2]), "v"(t[3]));
        *(u32x2*)&zh16[idx] = pv;
    };

    // ---- z init: z0 = F(sft=0), fused per-mt, swapped operands -------------
    {
        sh8 wb1[2], wb2[2];
#pragma unroll
        for (int nt = 0; nt < 2; ++nt) {
            const ushort* wp = wfB + 0 * 8192 + (w * 2 + nt) * 1024 + lane * 8;
            wb1[nt] = *(const sh8*)wp;
            wb2[nt] = *(const sh8*)(wp + 512);
        }
#pragma unroll
        for (int mt = 0; mt < 4; ++mt) {
            const ushort* ya = (lq < 3)
                ? &ypk[((0 * 3 + lq) * PTSB + mt * 16 + l15) * 8]
                : &zrow[0];
            sh8 yf = *(const sh8*)ya;
#pragma unroll
            for (int nt = 0; nt < 2; ++nt) {
                f32x4 t = (f32x4){0.f, 0.f, 0.f, 0.f};
                t = __builtin_amdgcn_mfma_f32_16x16x32_bf16(wb1[nt], yf, t, 0, 0, 0);
                t = __builtin_amdgcn_mfma_f32_16x16x32_bf16(wb2[nt], yf, t, 0, 0, 0);
                zstore4(mt, nt, t);
            }
        }
    }
    __syncthreads();

    // ---- 5 layers (2 barriers/layer) ---------------------------------------
    for (int layer = 0; layer < DEPTH; ++layer) {
        // publish shift layer+2 into buffer (layer+2)&1 (proven schedule).
        if (layer < DEPTH - 1 && w == ((layer + 2) & 3)) {
            sh8 k1;
            k1[0] = (short)(ushort)(pk1w & 0xFFFFu);
            k1[1] = (short)(ushort)(pk1w >> 16);
            k1[2] = (short)0x3F80;
            k1[3] = 0; k1[4] = 0; k1[5] = 0; k1[6] = 0; k1[7] = 0;
            ystore((layer + 2) & 1, pk0, k1, pk2);
        }

        f32x4 acc[4][2];
#pragma unroll
        for (int mt = 0; mt < 4; ++mt)
#pragma unroll
            for (int nt = 0; nt < 2; ++nt)
                acc[mt][nt] = (f32x4){0.f, 0.f, 0.f, 0.f};

        // NOT unrolled: full unroll hoists all 4 kq iterations' B-frag loads
        // which spills under the reg budget (R8 lesson).
#pragma unroll 1
        for (int kq = 0; kq < 4; ++kq) {
            // single rounded-bf16 Wfwd image: [layer][kq][nt][lane][j]
            const ushort* gp = gwB + (layer * 4 + kq) * 4096 + lane * 8;
            sh8 bh0 = *(const sh8*)(gp + (w * 2 + 0) * 512);
            sh8 bh1 = *(const sh8*)(gp + (w * 2 + 1) * 512);
#pragma unroll
            for (int mt = 0; mt < 4; ++mt) {
                int row  = mt * 16 + l15;
                int base = row * HIDDEN + (((kq * 4 + lq) ^ l15) << 3);
                sh8 ah = *(const sh8*)&zh16[base];
                acc[mt][0] = __builtin_amdgcn_mfma_f32_16x16x32_bf16(bh0, ah, acc[mt][0], 0, 0, 0);
                acc[mt][1] = __builtin_amdgcn_mfma_f32_16x16x32_bf16(bh1, ah, acc[mt][1], 0, 0, 0);
            }
        }
        __syncthreads();   // all z reads complete before overwrite

        // ctv: per nt, 4 consecutive cterm values at h = (w*2+nt)*16 + lq*4
        f32x4 ctv[2];
#pragma unroll
        for (int nt = 0; nt < 2; ++nt)
            ctv[nt] = *(const f32x4*)&cterm[(layer * BATCH + b) * HIDDEN
                                            + (w * 2 + nt) * 16 + lq * 4];

        // fused F phase + epilogue, per mt: z_next = (acc + ct) * F.
        {
            sh8 wb1[2], wb2[2];
#pragma unroll
            for (int nt = 0; nt < 2; ++nt) {
                const ushort* wp = wfB + (layer + 1) * 8192 + (w * 2 + nt) * 1024 + lane * 8;
                wb1[nt] = *(const sh8*)wp;
                wb2[nt] = *(const sh8*)(wp + 512);
            }
#pragma unroll
            for (int mt = 0; mt < 4; ++mt) {
                const ushort* ya = (lq < 3)
                    ? &ypk[((((layer + 1) & 1) * 3 + lq) * PTSB + mt * 16 + l15) * 8]
                    : &zrow[0];
                sh8 yf = *(const sh8*)ya;
#pragma unroll
                for (int nt = 0; nt < 2; ++nt) {
                    f32x4 t = (f32x4){0.f, 0.f, 0.f, 0.f};
                    t = __builtin_amdgcn_mfma_f32_16x16x32_bf16(wb1[nt], yf, t, 0, 0, 0);
                    t = __builtin_amdgcn_mfma_f32_16x16x32_bf16(wb2[nt], yf, t, 0, 0, 0);
                    f32x4 vv;
#pragma unroll
                    for (int r = 0; r < 4; ++r)
                        vv[r] = (acc[mt][nt][r] + ctv[nt][r]) * t[r];
                    zstore4(mt, nt, vv);
                }
            }
        }
        __syncthreads();   // writes visible before next layer's reads
    }

    // ---- final: out[p] = z · Wout + bout (psum overlays dead ypk) ----------
    float* psum = (float*)ypk;
    {
        int p = lane, qd = w;
        float accf = 0.0f;
#pragma unroll
        for (int cc = 0; cc < 4; ++cc) {
            int chunk = qd * 4 + cc;
            int base  = p * HIDDEN + ((chunk ^ (p & 15)) << 3);
            u32x4 hv = *(const u32x4*)&zh16[base];
            uint uh[4] = {hv.x, hv.y, hv.z, hv.w};
            const float* wp = Wout + chunk * 8;
#pragma unroll
            for (int q2 = 0; q2 < 4; ++q2) {
                float a0 = __uint_as_float(uh[q2] << 16);
                float a1 = __uint_as_float(uh[q2] & 0xFFFF0000u);
                accf = fmaf(a0, wp[q2 * 2], accf);
                accf = fmaf(a1, wp[q2 * 2 + 1], accf);
            }
        }
        psum[qd * 64 + p] = accf;
    }
    __syncthreads();
    if (tid < PTSB) {
        out[p0 + tid] = boutp[0] + psum[tid] + psum[64 + tid]
                                 + psum[128 + tid] + psum[192 + tid];
    }
}

// ---------------------------------------------------------------------------
extern "C" void kernel_launch(void* const* d_in, const int* in_sizes, int n_in,
                              void* d_out, int out_size, void* d_ws, size_t ws_size,
                              hipStream_t stream) {
    (void)in_sizes; (void)n_in; (void)out_size; (void)ws_size;
    const float* x     = (const float*)d_in[0];
    const float* a     = (const float*)d_in[1];
    const float* Wftr  = (const float*)d_in[2];
    const float* bftr  = (const float*)d_in[3];
    const float* Wfwd  = (const float*)d_in[4];
    const float* bfwd  = (const float*)d_in[5];
    const float* Wcode = (const float*)d_in[6];
    const float* bcode = (const float*)d_in[7];
    const float* Wout  = (const float*)d_in[8];
    const float* bout  = (const float*)d_in[9];

    float* out   = (float*)d_out;                    // [B*N]
    float* out_x = out + NPTS;                       // [B*N*2]
    float*  cterm = (float*)d_ws;                    // 5120 floats
    ushort* wfB = (ushort*)(cterm + DEPTH * BATCH * HIDDEN);  // 49152 ushorts
    ushort* gwB = wfB + 49152;                                // 81920 ushorts

    // SH normalization coefficients on host (deterministic per call)
    CoefTab ct;
    for (int s = 0; s < 6; ++s)
        for (int yk = 0; yk < 9; ++yk) {
            int mm = yk - 4, am = mm < 0 ? -mm : mm, l = am + s;
            double ratio = 1.0;
            for (int q = l - am + 1; q <= l + am; ++q) ratio *= (double)q;
            double norm = sqrt((2.0 * l + 1.0) / (4.0 * M_PI * ratio));
            double cf = (mm == 0) ? norm : ((am & 1) ? -1.0 : 1.0) * sqrt(2.0) * norm;
            ct.c[s * 9 + yk] = (float)cf;
        }

    int nprep = DEPTH * BATCH + 192 + 320;
    sinr_prep<<<nprep, BLOCK, 0, stream>>>(a, Wcode, bcode, bfwd, Wftr, bftr,
                                           Wfwd, ct, cterm, wfB, gwB);
    sinr_main<<<NPTS / PTSB, BLOCK, 0, stream>>>(
        x, wfB, gwB, cterm, Wout, bout, out, out_x);
}

// Round 14
// 163.627 us; speedup vs baseline: 1.0437x; 1.0437x over previous
//
#include <hip/hip_runtime.h>
#include <math.h>

#define DEPTH   5
#define HIDDEN  128
#define CODE    400
#define NFREQ   9
#define BATCH   8
#define NPTS    262144
#define PTSB    64
#define BLOCK   256

typedef __attribute__((ext_vector_type(8))) short sh8;
typedef __attribute__((ext_vector_type(4))) float f32x4;
typedef __attribute__((ext_vector_type(4))) uint  u32x4;
typedef __attribute__((ext_vector_type(2))) uint  u32x2;

struct CoefTab { float c[54]; };   // [s][yk] SH normalization, host-computed

__device__ __forceinline__ ushort f2bf(float f) {   // round-to-nearest-even
    union { float f; uint u; } v; v.f = f;
    uint r = v.u + 0x7fffu + ((v.u >> 16) & 1u);
    return (ushort)(r >> 16);
}

// ---------------------------------------------------------------------------
// Prep (identical to R6/R10 proven version). gwB = single rounded bf16 Wfwd.
// ---------------------------------------------------------------------------
__global__ void sinr_prep(const float* __restrict__ a,
                          const float* __restrict__ Wcode,
                          const float* __restrict__ bcode,
                          const float* __restrict__ bfwd,
                          const float* __restrict__ Wftr,
                          const float* __restrict__ bftr,
                          const float* __restrict__ Wfwd,
                          CoefTab ct,
                          float* __restrict__ cterm,
                          ushort* __restrict__ wfB,
                          ushort* __restrict__ gwB) {
    int blk = blockIdx.x, tid = threadIdx.x;
    if (blk < DEPTH * BATCH) {
        if (tid < HIDDEN) {
            int i = blk / BATCH, b = blk % BATCH, h = tid;
            const float* ar = a + b * CODE;
            const float* wr = Wcode + (i * HIDDEN + h) * CODE;
            float acc = bcode[i * HIDDEN + h] + bfwd[i * HIDDEN + h];
            for (int c = 0; c < CODE; c += 4) {
                float4 av = *(const float4*)(ar + c);
                float4 wv = *(const float4*)(wr + c);
                acc = fmaf(av.x, wv.x, acc);
                acc = fmaf(av.y, wv.y, acc);
                acc = fmaf(av.z, wv.z, acc);
                acc = fmaf(av.w, wv.w, acc);
            }
            cterm[(i * BATCH + b) * HIDDEN + h] = acc;
        }
    } else if (blk < DEPTH * BATCH + 192) {
        int e = (blk - DEPTH * BATCH) * BLOCK + tid;     // < 49152
        int j    = e & 7;
        int lane = (e >> 3) & 63;
        int t    = (e >> 9) & 1;
        int nt   = (e >> 10) & 7;
        int s    = e >> 13;                               // 0..5
        int g  = nt * 16 + (lane & 15);
        int kq = lane >> 4;
        float v = 0.0f;
        if (kq == 0 || kq == 2) {
            v = ct.c[s * 9 + j] * Wftr[(s * HIDDEN + g) * NFREQ + j];
        } else if (kq == 1) {
            if (j == 0 || j == 1)
                v = ct.c[s * 9 + 8] * Wftr[(s * HIDDEN + g) * NFREQ + 8];
            else if (j == 2)
                v = bftr[s * HIDDEN + g];
        }
        uint u = __float_as_uint(v);
        float rf = v - __uint_as_float(u & 0xFFFF0000u);
        wfB[e] = t ? f2bf(rf) : (ushort)(u >> 16);
    } else {
        int e = (blk - DEPTH * BATCH - 192) * BLOCK + tid;  // < 81920
        if (e < DEPTH * 4 * 8 * 512) {
            int j     = e & 7;
            int lane  = (e >> 3) & 63;
            int nt    = (e >> 9) & 7;
            int kq    = (e >> 12) & 3;
            int layer = e >> 14;
            int g = nt * 16 + (lane & 15);
            int h = kq * 32 + (lane >> 4) * 8 + j;
            gwB[e] = f2bf(Wfwd[(layer * HIDDEN + g) * HIDDEN + h]);
        }
    }
}

// ---------------------------------------------------------------------------
// Main. Recovery from R13's NaN: the only never-tested-together pair was
// {inline-asm v_cvt_pk_bf16_f32, bound-4 regalloc} (R9-R11 proved this
// structure at bound-4 with C-packing; R12 proved asm cvt_pk at bound-6).
// Suspect removed: zstore4 reverted to R11's pure-C f2bf packing (proven
// 91.9 us at bound-4). KEEP the reciprocal-multiply Legendre (proven
// bit-invisible in R12; pure arithmetic, bound-independent).
// Structure verbatim R11: swapped-MFMA transposed fragments, ypk dbuf,
// unroll-1 kq loop, fused F epilogue, launch_bounds(256,4).
// ---------------------------------------------------------------------------
__global__ __launch_bounds__(BLOCK, 4)
void sinr_main(const float* __restrict__ x,
               const ushort* __restrict__ wfB,
               const ushort* __restrict__ gwB,
               const float* __restrict__ cterm,
               const float* __restrict__ Wout,
               const float* __restrict__ boutp,
               float* __restrict__ out,
               float* __restrict__ out_x) {
    __shared__ __align__(16) ushort zh16[PTSB * HIDDEN];     // 16 KB
    __shared__ __align__(16) ushort ypk[2 * 3 * PTSB * 8];   // 6 KB (dbuf)
    __shared__ __align__(16) ushort zrow[8];

    const int tid  = threadIdx.x;
    const int lane = tid & 63;
    const int w    = tid >> 6;
    const int l15  = lane & 15, lq = lane >> 4;
    const int p0   = blockIdx.x * PTSB;
    const int b    = p0 >> 15;

    if (tid < 2 * PTSB) out_x[p0 * 2 + tid] = x[p0 * 2 + tid];
    if (tid < 8) zrow[tid] = 0;

    // staged pre-packed shift (wave w owns shift: w==0->4, 1->5, 2->2, 3->3)
    sh8 pk0, pk2;
    uint pk1w = 0;   // k1[0] | k1[1]<<16 (rest of k1 is constant)

    // store one packed shift triple into ypk buffer `buf`
    auto ystore = [&](int buf, const sh8& k0, const sh8& k1, const sh8& k2) {
        int off = (buf * 3 * PTSB + lane) * 8;
        *(sh8*)&ypk[off]                = k0;
        *(sh8*)&ypk[off + PTSB * 8]     = k1;
        *(sh8*)&ypk[off + 2 * PTSB * 8] = k2;
    };

    // ---- harmonics: every wave computes the full proven P/trig table ------
    {
        float th = x[(p0 + lane) * 2 + 0];
        float ph = x[(p0 + lane) * 2 + 1];
        float c  = cosf(ph);
        float somx2 = sqrtf(fmaxf(1.0f - c * c, 0.0f));
        float s1, c1;
        sincosf(th, &s1, &c1);
        float ctab[5], stab[5];
        ctab[0] = 1.0f; stab[0] = 0.0f;
        ctab[1] = c1;   stab[1] = s1;
#pragma unroll
        for (int k = 2; k <= 4; ++k) {
            ctab[k] = ctab[k - 1] * c1 - stab[k - 1] * s1;
            stab[k] = stab[k - 1] * c1 + ctab[k - 1] * s1;
        }
        float P[5][6];
        float pmm = 1.0f;
#pragma unroll
        for (int am = 0; am <= 4; ++am) {
            if (am > 0) pmm *= -(2.0f * am - 1.0f) * somx2;
            float pm2 = pmm;
            float pm1 = c * (2.0f * am + 1.0f) * pmm;
            P[am][0] = pm2;
            P[am][1] = pm1;
#pragma unroll
            for (int s = 2; s < 6; ++s) {
                int l = am + s;
                // divisor (l-am) == s is an unroll-time constant: multiply by
                // the folded reciprocal (s=2,4 exact; s=3,5 <=1 ulp on P —
                // invisible after bf16 truncation; proven R12).
                float pl = ((2.0f * l - 1.0f) * c * pm1
                            - (float)(l + am - 1) * pm2) * (1.0f / (float)s);
                P[am][s] = pl;
                pm2 = pm1;
                pm1 = pl;
            }
        }
        // verbatim proven pack loop, parameterized by the 5 P values
        auto mk = [&](float Pv0, float Pv1, float Pv2, float Pv3, float Pv4,
                      sh8& k0, sh8& k1, sh8& k2) {
            float Pv[5] = {Pv0, Pv1, Pv2, Pv3, Pv4};
            ushort yh[9], yl[9];
#pragma unroll
            for (int mm = -4; mm <= 4; ++mm) {
                int am = mm < 0 ? -mm : mm;
                float trig = (mm > 0) ? ctab[am] : ((mm < 0) ? stab[am] : 1.0f);
                float yv = Pv[am] * trig;
                uint u = __float_as_uint(yv);
                yh[mm + 4] = (ushort)(u >> 16);
                float rf = yv - __uint_as_float(u & 0xFFFF0000u);
                yl[mm + 4] = (ushort)(__float_as_uint(rf) >> 16);
            }
#pragma unroll
            for (int j = 0; j < 8; ++j) { k0[j] = (short)yh[j]; k2[j] = (short)yl[j]; }
            k1[0] = (short)yh[8]; k1[1] = (short)yl[8]; k1[2] = (short)0x3F80;
            k1[3] = 0; k1[4] = 0; k1[5] = 0; k1[6] = 0; k1[7] = 0;
        };
        sh8 t0, t1, t2;
        if (w == 0) {
            mk(P[0][0], P[1][0], P[2][0], P[3][0], P[4][0], t0, t1, t2);
            ystore(0, t0, t1, t2);
            mk(P[0][4], P[1][4], P[2][4], P[3][4], P[4][4], pk0, t1, pk2);
            pk1w = (uint)(ushort)t1[0] | ((uint)(ushort)t1[1] << 16);
        } else if (w == 1) {
            mk(P[0][1], P[1][1], P[2][1], P[3][1], P[4][1], t0, t1, t2);
            ystore(1, t0, t1, t2);
            mk(P[0][5], P[1][5], P[2][5], P[3][5], P[4][5], pk0, t1, pk2);
            pk1w = (uint)(ushort)t1[0] | ((uint)(ushort)t1[1] << 16);
        } else if (w == 2) {
            mk(P[0][2], P[1][2], P[2][2], P[3][2], P[4][2], pk0, t1, pk2);
            pk1w = (uint)(ushort)t1[0] | ((uint)(ushort)t1[1] << 16);
        } else {
            mk(P[0][3], P[1][3], P[2][3], P[3][3], P[4][3], pk0, t1, pk2);
            pk1w = (uint)(ushort)t1[0] | ((uint)(ushort)t1[1] << 16);
        }
    }
    __syncthreads();

    // z store, TRANSPOSED fragment: lane holds point row = mt*16+l15 and 4
    // consecutive h = (w*2+nt)*16 + lq*4 + r; one b64 write per (mt,nt).
    // Pure-C f2bf packing (R11-proven at bound-4; asm cvt_pk removed after
    // R13's NaN under bound-4 regalloc).
    auto zstore4 = [&](int mt, int nt, f32x4 t) {
        int row = mt * 16 + l15;
        int ch  = (w * 2 + nt) * 2 + (lq >> 1);
        int idx = row * HIDDEN + ((ch ^ l15) << 3) + (lq & 1) * 4;
        u32x2 pv;
        pv.x = (uint)f2bf(t[0]) | ((uint)f2bf(t[1]) << 16);
        pv.y = (uint)f2bf(t[2]) | ((uint)f2bf(t[3]) << 16);
        *(u32x2*)&zh16[idx] = pv;
    };

    // ---- z init: z0 = F(sft=0), fused per-mt, swapped operands -------------
    {
        sh8 wb1[2], wb2[2];
#pragma unroll
        for (int nt = 0; nt < 2; ++nt) {
            const ushort* wp = wfB + 0 * 8192 + (w * 2 + nt) * 1024 + lane * 8;
            wb1[nt] = *(const sh8*)wp;
            wb2[nt] = *(const sh8*)(wp + 512);
        }
#pragma unroll
        for (int mt = 0; mt < 4; ++mt) {
            const ushort* ya = (lq < 3)
                ? &ypk[((0 * 3 + lq) * PTSB + mt * 16 + l15) * 8]
                : &zrow[0];
            sh8 yf = *(const sh8*)ya;
#pragma unroll
            for (int nt = 0; nt < 2; ++nt) {
                f32x4 t = (f32x4){0.f, 0.f, 0.f, 0.f};
                t = __builtin_amdgcn_mfma_f32_16x16x32_bf16(wb1[nt], yf, t, 0, 0, 0);
                t = __builtin_amdgcn_mfma_f32_16x16x32_bf16(wb2[nt], yf, t, 0, 0, 0);
                zstore4(mt, nt, t);
            }
        }
    }
    __syncthreads();

    // ---- 5 layers (2 barriers/layer) ---------------------------------------
    for (int layer = 0; layer < DEPTH; ++layer) {
        // publish shift layer+2 into buffer (layer+2)&1 (proven schedule).
        if (layer < DEPTH - 1 && w == ((layer + 2) & 3)) {
            sh8 k1;
            k1[0] = (short)(ushort)(pk1w & 0xFFFFu);
            k1[1] = (short)(ushort)(pk1w >> 16);
            k1[2] = (short)0x3F80;
            k1[3] = 0; k1[4] = 0; k1[5] = 0; k1[6] = 0; k1[7] = 0;
            ystore((layer + 2) & 1, pk0, k1, pk2);
        }

        f32x4 acc[4][2];
#pragma unroll
        for (int mt = 0; mt < 4; ++mt)
#pragma unroll
            for (int nt = 0; nt < 2; ++nt)
                acc[mt][nt] = (f32x4){0.f, 0.f, 0.f, 0.f};

        // NOT unrolled: full unroll hoists all 4 kq iterations' B-frag loads
        // which spills under the bound-4 128-reg budget (R8 lesson).
#pragma unroll 1
        for (int kq = 0; kq < 4; ++kq) {
            // single rounded-bf16 Wfwd image: [layer][kq][nt][lane][j]
            const ushort* gp = gwB + (layer * 4 + kq) * 4096 + lane * 8;
            sh8 bh0 = *(const sh8*)(gp + (w * 2 + 0) * 512);
            sh8 bh1 = *(const sh8*)(gp + (w * 2 + 1) * 512);
#pragma unroll
            for (int mt = 0; mt < 4; ++mt) {
                int row  = mt * 16 + l15;
                int base = row * HIDDEN + (((kq * 4 + lq) ^ l15) << 3);
                sh8 ah = *(const sh8*)&zh16[base];
                acc[mt][0] = __builtin_amdgcn_mfma_f32_16x16x32_bf16(bh0, ah, acc[mt][0], 0, 0, 0);
                acc[mt][1] = __builtin_amdgcn_mfma_f32_16x16x32_bf16(bh1, ah, acc[mt][1], 0, 0, 0);
            }
        }
        __syncthreads();   // all z reads complete before overwrite

        // ctv: per nt, 4 consecutive cterm values at h = (w*2+nt)*16 + lq*4
        f32x4 ctv[2];
#pragma unroll
        for (int nt = 0; nt < 2; ++nt)
            ctv[nt] = *(const f32x4*)&cterm[(layer * BATCH + b) * HIDDEN
                                            + (w * 2 + nt) * 16 + lq * 4];

        // fused F phase + epilogue, per mt: z_next = (acc + ct) * F.
        {
            sh8 wb1[2], wb2[2];
#pragma unroll
            for (int nt = 0; nt < 2; ++nt) {
                const ushort* wp = wfB + (layer + 1) * 8192 + (w * 2 + nt) * 1024 + lane * 8;
                wb1[nt] = *(const sh8*)wp;
                wb2[nt] = *(const sh8*)(wp + 512);
            }
#pragma unroll
            for (int mt = 0; mt < 4; ++mt) {
                const ushort* ya = (lq < 3)
                    ? &ypk[((((layer + 1) & 1) * 3 + lq) * PTSB + mt * 16 + l15) * 8]
                    : &zrow[0];
                sh8 yf = *(const sh8*)ya;
#pragma unroll
                for (int nt = 0; nt < 2; ++nt) {
                    f32x4 t = (f32x4){0.f, 0.f, 0.f, 0.f};
                    t = __builtin_amdgcn_mfma_f32_16x16x32_bf16(wb1[nt], yf, t, 0, 0, 0);
                    t = __builtin_amdgcn_mfma_f32_16x16x32_bf16(wb2[nt], yf, t, 0, 0, 0);
                    f32x4 vv;
#pragma unroll
                    for (int r = 0; r < 4; ++r)
                        vv[r] = (acc[mt][nt][r] + ctv[nt][r]) * t[r];
                    zstore4(mt, nt, vv);
                }
            }
        }
        __syncthreads();   // writes visible before next layer's reads
    }

    // ---- final: out[p] = z · Wout + bout (psum overlays dead ypk) ----------
    float* psum = (float*)ypk;
    {
        int p = lane, qd = w;
        float accf = 0.0f;
#pragma unroll
        for (int cc = 0; cc < 4; ++cc) {
            int chunk = qd * 4 + cc;
            int base  = p * HIDDEN + ((chunk ^ (p & 15)) << 3);
            u32x4 hv = *(const u32x4*)&zh16[base];
            uint uh[4] = {hv.x, hv.y, hv.z, hv.w};
            const float* wp = Wout + chunk * 8;
#pragma unroll
            for (int q2 = 0; q2 < 4; ++q2) {
                float a0 = __uint_as_float(uh[q2] << 16);
                float a1 = __uint_as_float(uh[q2] & 0xFFFF0000u);
                accf = fmaf(a0, wp[q2 * 2], accf);
                accf = fmaf(a1, wp[q2 * 2 + 1], accf);
            }
        }
        psum[qd * 64 + p] = accf;
    }
    __syncthreads();
    if (tid < PTSB) {
        out[p0 + tid] = boutp[0] + psum[tid] + psum[64 + tid]
                                 + psum[128 + tid] + psum[192 + tid];
    }
}

// ---------------------------------------------------------------------------
extern "C" void kernel_launch(void* const* d_in, const int* in_sizes, int n_in,
                              void* d_out, int out_size, void* d_ws, size_t ws_size,
                              hipStream_t stream) {
    (void)in_sizes; (void)n_in; (void)out_size; (void)ws_size;
    const float* x     = (const float*)d_in[0];
    const float* a     = (const float*)d_in[1];
    const float* Wftr  = (const float*)d_in[2];
    const float* bftr  = (const float*)d_in[3];
    const float* Wfwd  = (const float*)d_in[4];
    const float* bfwd  = (const float*)d_in[5];
    const float* Wcode = (const float*)d_in[6];
    const float* bcode = (const float*)d_in[7];
    const float* Wout  = (const float*)d_in[8];
    const float* bout  = (const float*)d_in[9];

    float* out   = (float*)d_out;                    // [B*N]
    float* out_x = out + NPTS;                       // [B*N*2]
    float*  cterm = (float*)d_ws;                    // 5120 floats
    ushort* wfB = (ushort*)(cterm + DEPTH * BATCH * HIDDEN);  // 49152 ushorts
    ushort* gwB = wfB + 49152;                                // 81920 ushorts

    // SH normalization coefficients on host (deterministic per call)
    CoefTab ct;
    for (int s = 0; s < 6; ++s)
        for (int yk = 0; yk < 9; ++yk) {
            int mm = yk - 4, am = mm < 0 ? -mm : mm, l = am + s;
            double ratio = 1.0;
            for (int q = l - am + 1; q <= l + am; ++q) ratio *= (double)q;
            double norm = sqrt((2.0 * l + 1.0) / (4.0 * M_PI * ratio));
            double cf = (mm == 0) ? norm : ((am & 1) ? -1.0 : 1.0) * sqrt(2.0) * norm;
            ct.c[s * 9 + yk] = (float)cf;
        }

    int nprep = DEPTH * BATCH + 192 + 320;
    sinr_prep<<<nprep, BLOCK, 0, stream>>>(a, Wcode, bcode, bfwd, Wftr, bftr,
                                           Wfwd, ct, cterm, wfB, gwB);
    sinr_main<<<NPTS / PTSB, BLOCK, 0, stream>>>(
        x, wfB, gwB, cterm, Wout, bout, out, out_x);
}

// Round 15
// 160.755 us; speedup vs baseline: 1.0624x; 1.0179x over previous
//
#include <hip/hip_runtime.h>
#include <math.h>

#define DEPTH   5
#define HIDDEN  128
#define CODE    400
#define NFREQ   9
#define BATCH   8
#define NPTS    262144
#define PTSB    64
#define BLOCK   256

typedef __attribute__((ext_vector_type(8))) short sh8;
typedef __attribute__((ext_vector_type(4))) float f32x4;
typedef __attribute__((ext_vector_type(4))) uint  u32x4;
typedef __attribute__((ext_vector_type(2))) uint  u32x2;

struct CoefTab { float c[54]; };   // [s][yk] SH normalization, host-computed

__device__ __forceinline__ ushort f2bf(float f) {   // round-to-nearest-even
    union { float f; uint u; } v; v.f = f;
    uint r = v.u + 0x7fffu + ((v.u >> 16) & 1u);
    return (ushort)(r >> 16);
}

// ---------------------------------------------------------------------------
// Prep (identical to R6/R10 proven version). gwB = single rounded bf16 Wfwd.
// ---------------------------------------------------------------------------
__global__ void sinr_prep(const float* __restrict__ a,
                          const float* __restrict__ Wcode,
                          const float* __restrict__ bcode,
                          const float* __restrict__ bfwd,
                          const float* __restrict__ Wftr,
                          const float* __restrict__ bftr,
                          const float* __restrict__ Wfwd,
                          CoefTab ct,
                          float* __restrict__ cterm,
                          ushort* __restrict__ wfB,
                          ushort* __restrict__ gwB) {
    int blk = blockIdx.x, tid = threadIdx.x;
    if (blk < DEPTH * BATCH) {
        if (tid < HIDDEN) {
            int i = blk / BATCH, b = blk % BATCH, h = tid;
            const float* ar = a + b * CODE;
            const float* wr = Wcode + (i * HIDDEN + h) * CODE;
            float acc = bcode[i * HIDDEN + h] + bfwd[i * HIDDEN + h];
            for (int c = 0; c < CODE; c += 4) {
                float4 av = *(const float4*)(ar + c);
                float4 wv = *(const float4*)(wr + c);
                acc = fmaf(av.x, wv.x, acc);
                acc = fmaf(av.y, wv.y, acc);
                acc = fmaf(av.z, wv.z, acc);
                acc = fmaf(av.w, wv.w, acc);
            }
            cterm[(i * BATCH + b) * HIDDEN + h] = acc;
        }
    } else if (blk < DEPTH * BATCH + 192) {
        int e = (blk - DEPTH * BATCH) * BLOCK + tid;     // < 49152
        int j    = e & 7;
        int lane = (e >> 3) & 63;
        int t    = (e >> 9) & 1;
        int nt   = (e >> 10) & 7;
        int s    = e >> 13;                               // 0..5
        int g  = nt * 16 + (lane & 15);
        int kq = lane >> 4;
        float v = 0.0f;
        if (kq == 0 || kq == 2) {
            v = ct.c[s * 9 + j] * Wftr[(s * HIDDEN + g) * NFREQ + j];
        } else if (kq == 1) {
            if (j == 0 || j == 1)
                v = ct.c[s * 9 + 8] * Wftr[(s * HIDDEN + g) * NFREQ + 8];
            else if (j == 2)
                v = bftr[s * HIDDEN + g];
        }
        uint u = __float_as_uint(v);
        float rf = v - __uint_as_float(u & 0xFFFF0000u);
        wfB[e] = t ? f2bf(rf) : (ushort)(u >> 16);
    } else {
        int e = (blk - DEPTH * BATCH - 192) * BLOCK + tid;  // < 81920
        if (e < DEPTH * 4 * 8 * 512) {
            int j     = e & 7;
            int lane  = (e >> 3) & 63;
            int nt    = (e >> 9) & 7;
            int kq    = (e >> 12) & 3;
            int layer = e >> 14;
            int g = nt * 16 + (lane & 15);
            int h = kq * 32 + (lane >> 4) * 8 + j;
            gwB[e] = f2bf(Wfwd[(layer * HIDDEN + g) * HIDDEN + h]);
        }
    }
}

// ---------------------------------------------------------------------------
// Main. vs R14 (proven): z PING-PONG double buffer -> ONE barrier per layer.
// The 2-barriers/layer skeleton existed only because z_next overwrote z in
// place (barrier #1 = WAR, #2 = visibility). With zA/zB, layer l reads
// buf[l&1] and writes buf[(l+1)&1] -> no WAR; only the end-of-layer
// visibility barrier remains. Cross-wave deps re-derived: ypk publish at
// top of iter l (buf l&1) vs readers (epilogue l-1 reads l&1 BEFORE the
// end-of-(l-1) barrier; epilogue l reads (l+1)&1, a different buffer) all
// separated by >=1 barrier. Final reads zB (layer 4 writes it). Barriers
// 12 -> 7. LDS 23 -> 38.9 KB, still 4 blocks/CU (R4-R9 proven footprint).
// Zero arithmetic change; everything else verbatim R14.
// ---------------------------------------------------------------------------
__global__ __launch_bounds__(BLOCK, 4)
void sinr_main(const float* __restrict__ x,
               const ushort* __restrict__ wfB,
               const ushort* __restrict__ gwB,
               const float* __restrict__ cterm,
               const float* __restrict__ Wout,
               const float* __restrict__ boutp,
               float* __restrict__ out,
               float* __restrict__ out_x) {
    __shared__ __align__(16) ushort zA[PTSB * HIDDEN];      // 16 KB
    __shared__ __align__(16) ushort zB[PTSB * HIDDEN];      // 16 KB
    __shared__ __align__(16) ushort ypk[2 * 3 * PTSB * 8];  // 6 KB (dbuf)
    __shared__ __align__(16) ushort zrow[8];

    const int tid  = threadIdx.x;
    const int lane = tid & 63;
    const int w    = tid >> 6;
    const int l15  = lane & 15, lq = lane >> 4;
    const int p0   = blockIdx.x * PTSB;
    const int b    = p0 >> 15;

    if (tid < 2 * PTSB) out_x[p0 * 2 + tid] = x[p0 * 2 + tid];
    if (tid < 8) zrow[tid] = 0;

    // staged pre-packed shift (wave w owns shift: w==0->4, 1->5, 2->2, 3->3)
    sh8 pk0, pk2;
    uint pk1w = 0;   // k1[0] | k1[1]<<16 (rest of k1 is constant)

    // store one packed shift triple into ypk buffer `buf`
    auto ystore = [&](int buf, const sh8& k0, const sh8& k1, const sh8& k2) {
        int off = (buf * 3 * PTSB + lane) * 8;
        *(sh8*)&ypk[off]                = k0;
        *(sh8*)&ypk[off + PTSB * 8]     = k1;
        *(sh8*)&ypk[off + 2 * PTSB * 8] = k2;
    };

    // ---- harmonics: every wave computes the full proven P/trig table ------
    {
        float th = x[(p0 + lane) * 2 + 0];
        float ph = x[(p0 + lane) * 2 + 1];
        float c  = cosf(ph);
        float somx2 = sqrtf(fmaxf(1.0f - c * c, 0.0f));
        float s1, c1;
        sincosf(th, &s1, &c1);
        float ctab[5], stab[5];
        ctab[0] = 1.0f; stab[0] = 0.0f;
        ctab[1] = c1;   stab[1] = s1;
#pragma unroll
        for (int k = 2; k <= 4; ++k) {
            ctab[k] = ctab[k - 1] * c1 - stab[k - 1] * s1;
            stab[k] = stab[k - 1] * c1 + ctab[k - 1] * s1;
        }
        float P[5][6];
        float pmm = 1.0f;
#pragma unroll
        for (int am = 0; am <= 4; ++am) {
            if (am > 0) pmm *= -(2.0f * am - 1.0f) * somx2;
            float pm2 = pmm;
            float pm1 = c * (2.0f * am + 1.0f) * pmm;
            P[am][0] = pm2;
            P[am][1] = pm1;
#pragma unroll
            for (int s = 2; s < 6; ++s) {
                int l = am + s;
                // divisor (l-am) == s is an unroll-time constant: multiply by
                // the folded reciprocal (s=2,4 exact; s=3,5 <=1 ulp on P —
                // invisible after bf16 truncation; proven R12/R14).
                float pl = ((2.0f * l - 1.0f) * c * pm1
                            - (float)(l + am - 1) * pm2) * (1.0f / (float)s);
                P[am][s] = pl;
                pm2 = pm1;
                pm1 = pl;
            }
        }
        // verbatim proven pack loop, parameterized by the 5 P values
        auto mk = [&](float Pv0, float Pv1, float Pv2, float Pv3, float Pv4,
                      sh8& k0, sh8& k1, sh8& k2) {
            float Pv[5] = {Pv0, Pv1, Pv2, Pv3, Pv4};
            ushort yh[9], yl[9];
#pragma unroll
            for (int mm = -4; mm <= 4; ++mm) {
                int am = mm < 0 ? -mm : mm;
                float trig = (mm > 0) ? ctab[am] : ((mm < 0) ? stab[am] : 1.0f);
                float yv = Pv[am] * trig;
                uint u = __float_as_uint(yv);
                yh[mm + 4] = (ushort)(u >> 16);
                float rf = yv - __uint_as_float(u & 0xFFFF0000u);
                yl[mm + 4] = (ushort)(__float_as_uint(rf) >> 16);
            }
#pragma unroll
            for (int j = 0; j < 8; ++j) { k0[j] = (short)yh[j]; k2[j] = (short)yl[j]; }
            k1[0] = (short)yh[8]; k1[1] = (short)yl[8]; k1[2] = (short)0x3F80;
            k1[3] = 0; k1[4] = 0; k1[5] = 0; k1[6] = 0; k1[7] = 0;
        };
        sh8 t0, t1, t2;
        if (w == 0) {
            mk(P[0][0], P[1][0], P[2][0], P[3][0], P[4][0], t0, t1, t2);
            ystore(0, t0, t1, t2);
            mk(P[0][4], P[1][4], P[2][4], P[3][4], P[4][4], pk0, t1, pk2);
            pk1w = (uint)(ushort)t1[0] | ((uint)(ushort)t1[1] << 16);
        } else if (w == 1) {
            mk(P[0][1], P[1][1], P[2][1], P[3][1], P[4][1], t0, t1, t2);
            ystore(1, t0, t1, t2);
            mk(P[0][5], P[1][5], P[2][5], P[3][5], P[4][5], pk0, t1, pk2);
            pk1w = (uint)(ushort)t1[0] | ((uint)(ushort)t1[1] << 16);
        } else if (w == 2) {
            mk(P[0][2], P[1][2], P[2][2], P[3][2], P[4][2], pk0, t1, pk2);
            pk1w = (uint)(ushort)t1[0] | ((uint)(ushort)t1[1] << 16);
        } else {
            mk(P[0][3], P[1][3], P[2][3], P[3][3], P[4][3], pk0, t1, pk2);
            pk1w = (uint)(ushort)t1[0] | ((uint)(ushort)t1[1] << 16);
        }
    }
    __syncthreads();

    // z store into buffer zbuf, TRANSPOSED fragment: lane holds point row =
    // mt*16+l15 and 4 consecutive h = (w*2+nt)*16 + lq*4 + r; one b64 write.
    // Pure-C f2bf packing (R11/R14-proven at bound-4).
    auto zstore4 = [&](ushort* zbuf, int mt, int nt, f32x4 t) {
        int row = mt * 16 + l15;
        int ch  = (w * 2 + nt) * 2 + (lq >> 1);
        int idx = row * HIDDEN + ((ch ^ l15) << 3) + (lq & 1) * 4;
        u32x2 pv;
        pv.x = (uint)f2bf(t[0]) | ((uint)f2bf(t[1]) << 16);
        pv.y = (uint)f2bf(t[2]) | ((uint)f2bf(t[3]) << 16);
        *(u32x2*)&zbuf[idx] = pv;
    };

    // ---- z init: z0 = F(sft=0) -> zA, fused per-mt, swapped operands -------
    {
        sh8 wb1[2], wb2[2];
#pragma unroll
        for (int nt = 0; nt < 2; ++nt) {
            const ushort* wp = wfB + 0 * 8192 + (w * 2 + nt) * 1024 + lane * 8;
            wb1[nt] = *(const sh8*)wp;
            wb2[nt] = *(const sh8*)(wp + 512);
        }
#pragma unroll
        for (int mt = 0; mt < 4; ++mt) {
            const ushort* ya = (lq < 3)
                ? &ypk[((0 * 3 + lq) * PTSB + mt * 16 + l15) * 8]
                : &zrow[0];
            sh8 yf = *(const sh8*)ya;
#pragma unroll
            for (int nt = 0; nt < 2; ++nt) {
                f32x4 t = (f32x4){0.f, 0.f, 0.f, 0.f};
                t = __builtin_amdgcn_mfma_f32_16x16x32_bf16(wb1[nt], yf, t, 0, 0, 0);
                t = __builtin_amdgcn_mfma_f32_16x16x32_bf16(wb2[nt], yf, t, 0, 0, 0);
                zstore4(zA, mt, nt, t);
            }
        }
    }
    __syncthreads();

    // ---- 5 layers (ONE barrier per layer; z ping-pong) ---------------------
    for (int layer = 0; layer < DEPTH; ++layer) {
        ushort* zin  = (layer & 1) ? zB : zA;
        ushort* zout = (layer & 1) ? zA : zB;

        // publish shift layer+2 into ypk buffer (layer+2)&1 (proven schedule;
        // its last reader, epilogue of iter layer-1, is behind the
        // end-of-layer-(layer-1) barrier).
        if (layer < DEPTH - 1 && w == ((layer + 2) & 3)) {
            sh8 k1;
            k1[0] = (short)(ushort)(pk1w & 0xFFFFu);
            k1[1] = (short)(ushort)(pk1w >> 16);
            k1[2] = (short)0x3F80;
            k1[3] = 0; k1[4] = 0; k1[5] = 0; k1[6] = 0; k1[7] = 0;
            ystore((layer + 2) & 1, pk0, k1, pk2);
        }

        f32x4 acc[4][2];
#pragma unroll
        for (int mt = 0; mt < 4; ++mt)
#pragma unroll
            for (int nt = 0; nt < 2; ++nt)
                acc[mt][nt] = (f32x4){0.f, 0.f, 0.f, 0.f};

        // NOT unrolled: full unroll hoists all 4 kq iterations' B-frag loads
        // which spills under the bound-4 128-reg budget (R8 lesson).
#pragma unroll 1
        for (int kq = 0; kq < 4; ++kq) {
            // single rounded-bf16 Wfwd image: [layer][kq][nt][lane][j]
            const ushort* gp = gwB + (layer * 4 + kq) * 4096 + lane * 8;
            sh8 bh0 = *(const sh8*)(gp + (w * 2 + 0) * 512);
            sh8 bh1 = *(const sh8*)(gp + (w * 2 + 1) * 512);
#pragma unroll
            for (int mt = 0; mt < 4; ++mt) {
                int row  = mt * 16 + l15;
                int base = row * HIDDEN + (((kq * 4 + lq) ^ l15) << 3);
                sh8 ah = *(const sh8*)&zin[base];
                acc[mt][0] = __builtin_amdgcn_mfma_f32_16x16x32_bf16(bh0, ah, acc[mt][0], 0, 0, 0);
                acc[mt][1] = __builtin_amdgcn_mfma_f32_16x16x32_bf16(bh1, ah, acc[mt][1], 0, 0, 0);
            }
        }
        // NO barrier here: epilogue writes zout (the OTHER buffer) — no WAR.

        // ctv: per nt, 4 consecutive cterm values at h = (w*2+nt)*16 + lq*4
        f32x4 ctv[2];
#pragma unroll
        for (int nt = 0; nt < 2; ++nt)
            ctv[nt] = *(const f32x4*)&cterm[(layer * BATCH + b) * HIDDEN
                                            + (w * 2 + nt) * 16 + lq * 4];

        // fused F phase + epilogue, per mt: z_next = (acc + ct) * F -> zout.
        {
            sh8 wb1[2], wb2[2];
#pragma unroll
            for (int nt = 0; nt < 2; ++nt) {
                const ushort* wp = wfB + (layer + 1) * 8192 + (w * 2 + nt) * 1024 + lane * 8;
                wb1[nt] = *(const sh8*)wp;
                wb2[nt] = *(const sh8*)(wp + 512);
            }
#pragma unroll
            for (int mt = 0; mt < 4; ++mt) {
                const ushort* ya = (lq < 3)
                    ? &ypk[((((layer + 1) & 1) * 3 + lq) * PTSB + mt * 16 + l15) * 8]
                    : &zrow[0];
                sh8 yf = *(const sh8*)ya;
#pragma unroll
                for (int nt = 0; nt < 2; ++nt) {
                    f32x4 t = (f32x4){0.f, 0.f, 0.f, 0.f};
                    t = __builtin_amdgcn_mfma_f32_16x16x32_bf16(wb1[nt], yf, t, 0, 0, 0);
                    t = __builtin_amdgcn_mfma_f32_16x16x32_bf16(wb2[nt], yf, t, 0, 0, 0);
                    f32x4 vv;
#pragma unroll
                    for (int r = 0; r < 4; ++r)
                        vv[r] = (acc[mt][nt][r] + ctv[nt][r]) * t[r];
                    zstore4(zout, mt, nt, vv);
                }
            }
        }
        __syncthreads();   // zout visible before next layer's reads
    }

    // ---- final: out[p] = z · Wout + bout; z is in zB (layer 4 wrote it) ----
    float* psum = (float*)ypk;
    {
        int p = lane, qd = w;
        float accf = 0.0f;
#pragma unroll
        for (int cc = 0; cc < 4; ++cc) {
            int chunk = qd * 4 + cc;
            int base  = p * HIDDEN + ((chunk ^ (p & 15)) << 3);
            u32x4 hv = *(const u32x4*)&zB[base];
            uint uh[4] = {hv.x, hv.y, hv.z, hv.w};
            const float* wp = Wout + chunk * 8;
#pragma unroll
            for (int q2 = 0; q2 < 4; ++q2) {
                float a0 = __uint_as_float(uh[q2] << 16);
                float a1 = __uint_as_float(uh[q2] & 0xFFFF0000u);
                accf = fmaf(a0, wp[q2 * 2], accf);
                accf = fmaf(a1, wp[q2 * 2 + 1], accf);
            }
        }
        psum[qd * 64 + p] = accf;
    }
    __syncthreads();
    if (tid < PTSB) {
        out[p0 + tid] = boutp[0] + psum[tid] + psum[64 + tid]
                                 + psum[128 + tid] + psum[192 + tid];
    }
}

// ---------------------------------------------------------------------------
extern "C" void kernel_launch(void* const* d_in, const int* in_sizes, int n_in,
                              void* d_out, int out_size, void* d_ws, size_t ws_size,
                              hipStream_t stream) {
    (void)in_sizes; (void)n_in; (void)out_size; (void)ws_size;
    const float* x     = (const float*)d_in[0];
    const float* a     = (const float*)d_in[1];
    const float* Wftr  = (const float*)d_in[2];
    const float* bftr  = (const float*)d_in[3];
    const float* Wfwd  = (const float*)d_in[4];
    const float* bfwd  = (const float*)d_in[5];
    const float* Wcode = (const float*)d_in[6];
    const float* bcode = (const float*)d_in[7];
    const float* Wout  = (const float*)d_in[8];
    const float* bout  = (const float*)d_in[9];

    float* out   = (float*)d_out;                    // [B*N]
    float* out_x = out + NPTS;                       // [B*N*2]
    float*  cterm = (float*)d_ws;                    // 5120 floats
    ushort* wfB = (ushort*)(cterm + DEPTH * BATCH * HIDDEN);  // 49152 ushorts
    ushort* gwB = wfB + 49152;                                // 81920 ushorts

    // SH normalization coefficients on host (deterministic per call)
    CoefTab ct;
    for (int s = 0; s < 6; ++s)
        for (int yk = 0; yk < 9; ++yk) {
            int mm = yk - 4, am = mm < 0 ? -mm : mm, l = am + s;
            double ratio = 1.0;
            for (int q = l - am + 1; q <= l + am; ++q) ratio *= (double)q;
            double norm = sqrt((2.0 * l + 1.0) / (4.0 * M_PI * ratio));
            double cf = (mm == 0) ? norm : ((am & 1) ? -1.0 : 1.0) * sqrt(2.0) * norm;
            ct.c[s * 9 + yk] = (float)cf;
        }

    int nprep = DEPTH * BATCH + 192 + 320;
    sinr_prep<<<nprep, BLOCK, 0, stream>>>(a, Wcode, bcode, bfwd, Wftr, bftr,
                                           Wfwd, ct, cterm, wfB, gwB);
    sinr_main<<<NPTS / PTSB, BLOCK, 0, stream>>>(
        x, wfB, gwB, cterm, Wout, bout, out, out_x);
}

// Round 16
// 143.235 us; speedup vs baseline: 1.1923x; 1.1223x over previous
//
#include <hip/hip_runtime.h>
#include <math.h>

#define DEPTH   5
#define HIDDEN  128
#define CODE    400
#define NFREQ   9
#define BATCH   8
#define NPTS    262144
#define PTSB    64
#define BLOCK   256

typedef __attribute__((ext_vector_type(8))) short sh8;
typedef __attribute__((ext_vector_type(4))) float f32x4;
typedef __attribute__((ext_vector_type(4))) uint  u32x4;
typedef __attribute__((ext_vector_type(2))) uint  u32x2;
typedef __bf16 bf16x2 __attribute__((ext_vector_type(2)));

struct CoefTab { float c[54]; };   // [s][yk] SH normalization, host-computed

__device__ __forceinline__ ushort f2bf(float f) {   // round-to-nearest-even
    union { float f; uint u; } v; v.f = f;
    uint r = v.u + 0x7fffu + ((v.u >> 16) & 1u);
    return (ushort)(r >> 16);
}

// ---------------------------------------------------------------------------
// Prep. vs R15: wfB is a SINGLE RNE-rounded image (24576 ushorts, was
// 49152 split hi/lo). The y split (yh/y8h/y8l/yl) lives in ypk's k-slots
// and is unchanged; only the filter COEFFICIENTS are rounded — the same
// transform R6 proved absmax-invisible for Wfwd. gwB unchanged (single
// rounded Wfwd image).
// ---------------------------------------------------------------------------
__global__ void sinr_prep(const float* __restrict__ a,
                          const float* __restrict__ Wcode,
                          const float* __restrict__ bcode,
                          const float* __restrict__ bfwd,
                          const float* __restrict__ Wftr,
                          const float* __restrict__ bftr,
                          const float* __restrict__ Wfwd,
                          CoefTab ct,
                          float* __restrict__ cterm,
                          ushort* __restrict__ wfB,
                          ushort* __restrict__ gwB) {
    int blk = blockIdx.x, tid = threadIdx.x;
    if (blk < DEPTH * BATCH) {
        if (tid < HIDDEN) {
            int i = blk / BATCH, b = blk % BATCH, h = tid;
            const float* ar = a + b * CODE;
            const float* wr = Wcode + (i * HIDDEN + h) * CODE;
            float acc = bcode[i * HIDDEN + h] + bfwd[i * HIDDEN + h];
            for (int c = 0; c < CODE; c += 4) {
                float4 av = *(const float4*)(ar + c);
                float4 wv = *(const float4*)(wr + c);
                acc = fmaf(av.x, wv.x, acc);
                acc = fmaf(av.y, wv.y, acc);
                acc = fmaf(av.z, wv.z, acc);
                acc = fmaf(av.w, wv.w, acc);
            }
            cterm[(i * BATCH + b) * HIDDEN + h] = acc;
        }
    } else if (blk < DEPTH * BATCH + 96) {
        int e = (blk - DEPTH * BATCH) * BLOCK + tid;     // < 24576
        int j    = e & 7;
        int lane = (e >> 3) & 63;
        int nt   = (e >> 9) & 7;
        int s    = e >> 12;                               // 0..5
        int g  = nt * 16 + (lane & 15);
        int kq = lane >> 4;
        float v = 0.0f;
        if (kq == 0 || kq == 2) {
            v = ct.c[s * 9 + j] * Wftr[(s * HIDDEN + g) * NFREQ + j];
        } else if (kq == 1) {
            if (j == 0 || j == 1)
                v = ct.c[s * 9 + 8] * Wftr[(s * HIDDEN + g) * NFREQ + 8];
            else if (j == 2)
                v = bftr[s * HIDDEN + g];
        }
        wfB[e] = f2bf(v);
    } else {
        int e = (blk - DEPTH * BATCH - 96) * BLOCK + tid;  // < 81920
        if (e < DEPTH * 4 * 8 * 512) {
            int j     = e & 7;
            int lane  = (e >> 3) & 63;
            int nt    = (e >> 9) & 7;
            int kq    = (e >> 12) & 3;
            int layer = e >> 14;
            int g = nt * 16 + (lane & 15);
            int h = kq * 32 + (lane >> 4) * 8 + j;
            gwB[e] = f2bf(Wfwd[(layer * HIDDEN + g) * HIDDEN + h]);
        }
    }
}

// ---------------------------------------------------------------------------
// Main. vs R15 (88.7 us proven): two independent cuts, schedule untouched
// (z ping-pong 1-barrier/layer, ypk dbuf, unroll-1 kq loop, bound-4):
//  * Single-image F filter: epilogue MFMAs 2 -> 1 per (mt,nt) — total
//    MFMA 248 -> 208 (-16%); wb load halves (-8 regs in epilogue window).
//    y precision (yh/y8h/y8l/yl k-slots) fully preserved; only the filter
//    coefficients are RNE-rounded (R6 precedent: absmax-invisible).
//  * zstore4 via native __bf16 casts: bit-exact RNE (same as f2bf on all
//    values here); lets the COMPILER emit v_cvt_pk_bf16_f32 with correct
//    regalloc (the safe form of R12's +cvt_pk, avoiding R13's asm NaN).
// ---------------------------------------------------------------------------
__global__ __launch_bounds__(BLOCK, 4)
void sinr_main(const float* __restrict__ x,
               const ushort* __restrict__ wfB,
               const ushort* __restrict__ gwB,
               const float* __restrict__ cterm,
               const float* __restrict__ Wout,
               const float* __restrict__ boutp,
               float* __restrict__ out,
               float* __restrict__ out_x) {
    __shared__ __align__(16) ushort zA[PTSB * HIDDEN];      // 16 KB
    __shared__ __align__(16) ushort zB[PTSB * HIDDEN];      // 16 KB
    __shared__ __align__(16) ushort ypk[2 * 3 * PTSB * 8];  // 6 KB (dbuf)
    __shared__ __align__(16) ushort zrow[8];

    const int tid  = threadIdx.x;
    const int lane = tid & 63;
    const int w    = tid >> 6;
    const int l15  = lane & 15, lq = lane >> 4;
    const int p0   = blockIdx.x * PTSB;
    const int b    = p0 >> 15;

    if (tid < 2 * PTSB) out_x[p0 * 2 + tid] = x[p0 * 2 + tid];
    if (tid < 8) zrow[tid] = 0;

    // staged pre-packed shift (wave w owns shift: w==0->4, 1->5, 2->2, 3->3)
    sh8 pk0, pk2;
    uint pk1w = 0;   // k1[0] | k1[1]<<16 (rest of k1 is constant)

    // store one packed shift triple into ypk buffer `buf`
    auto ystore = [&](int buf, const sh8& k0, const sh8& k1, const sh8& k2) {
        int off = (buf * 3 * PTSB + lane) * 8;
        *(sh8*)&ypk[off]                = k0;
        *(sh8*)&ypk[off + PTSB * 8]     = k1;
        *(sh8*)&ypk[off + 2 * PTSB * 8] = k2;
    };

    // ---- harmonics: every wave computes the full proven P/trig table ------
    {
        float th = x[(p0 + lane) * 2 + 0];
        float ph = x[(p0 + lane) * 2 + 1];
        float c  = cosf(ph);
        float somx2 = sqrtf(fmaxf(1.0f - c * c, 0.0f));
        float s1, c1;
        sincosf(th, &s1, &c1);
        float ctab[5], stab[5];
        ctab[0] = 1.0f; stab[0] = 0.0f;
        ctab[1] = c1;   stab[1] = s1;
#pragma unroll
        for (int k = 2; k <= 4; ++k) {
            ctab[k] = ctab[k - 1] * c1 - stab[k - 1] * s1;
            stab[k] = stab[k - 1] * c1 + ctab[k - 1] * s1;
        }
        float P[5][6];
        float pmm = 1.0f;
#pragma unroll
        for (int am = 0; am <= 4; ++am) {
            if (am > 0) pmm *= -(2.0f * am - 1.0f) * somx2;
            float pm2 = pmm;
            float pm1 = c * (2.0f * am + 1.0f) * pmm;
            P[am][0] = pm2;
            P[am][1] = pm1;
#pragma unroll
            for (int s = 2; s < 6; ++s) {
                int l = am + s;
                // divisor (l-am) == s is an unroll-time constant: multiply by
                // the folded reciprocal (s=2,4 exact; s=3,5 <=1 ulp on P —
                // invisible after bf16 rounding; proven R12/R14).
                float pl = ((2.0f * l - 1.0f) * c * pm1
                            - (float)(l + am - 1) * pm2) * (1.0f / (float)s);
                P[am][s] = pl;
                pm2 = pm1;
                pm1 = pl;
            }
        }
        // verbatim proven pack loop, parameterized by the 5 P values
        auto mk = [&](float Pv0, float Pv1, float Pv2, float Pv3, float Pv4,
                      sh8& k0, sh8& k1, sh8& k2) {
            float Pv[5] = {Pv0, Pv1, Pv2, Pv3, Pv4};
            ushort yh[9], yl[9];
#pragma unroll
            for (int mm = -4; mm <= 4; ++mm) {
                int am = mm < 0 ? -mm : mm;
                float trig = (mm > 0) ? ctab[am] : ((mm < 0) ? stab[am] : 1.0f);
                float yv = Pv[am] * trig;
                uint u = __float_as_uint(yv);
                yh[mm + 4] = (ushort)(u >> 16);
                float rf = yv - __uint_as_float(u & 0xFFFF0000u);
                yl[mm + 4] = (ushort)(__float_as_uint(rf) >> 16);
            }
#pragma unroll
            for (int j = 0; j < 8; ++j) { k0[j] = (short)yh[j]; k2[j] = (short)yl[j]; }
            k1[0] = (short)yh[8]; k1[1] = (short)yl[8]; k1[2] = (short)0x3F80;
            k1[3] = 0; k1[4] = 0; k1[5] = 0; k1[6] = 0; k1[7] = 0;
        };
        sh8 t0, t1, t2;
        if (w == 0) {
            mk(P[0][0], P[1][0], P[2][0], P[3][0], P[4][0], t0, t1, t2);
            ystore(0, t0, t1, t2);
            mk(P[0][4], P[1][4], P[2][4], P[3][4], P[4][4], pk0, t1, pk2);
            pk1w = (uint)(ushort)t1[0] | ((uint)(ushort)t1[1] << 16);
        } else if (w == 1) {
            mk(P[0][1], P[1][1], P[2][1], P[3][1], P[4][1], t0, t1, t2);
            ystore(1, t0, t1, t2);
            mk(P[0][5], P[1][5], P[2][5], P[3][5], P[4][5], pk0, t1, pk2);
            pk1w = (uint)(ushort)t1[0] | ((uint)(ushort)t1[1] << 16);
        } else if (w == 2) {
            mk(P[0][2], P[1][2], P[2][2], P[3][2], P[4][2], pk0, t1, pk2);
            pk1w = (uint)(ushort)t1[0] | ((uint)(ushort)t1[1] << 16);
        } else {
            mk(P[0][3], P[1][3], P[2][3], P[3][3], P[4][3], pk0, t1, pk2);
            pk1w = (uint)(ushort)t1[0] | ((uint)(ushort)t1[1] << 16);
        }
    }
    __syncthreads();

    // z store into buffer zbuf, TRANSPOSED fragment: lane holds point row =
    // mt*16+l15 and 4 consecutive h = (w*2+nt)*16 + lq*4 + r; one b64 write.
    // Native __bf16 casts (RNE, bit-identical to f2bf here); compiler is
    // free to emit v_cvt_pk_bf16_f32 with proper regalloc.
    auto zstore4 = [&](ushort* zbuf, int mt, int nt, f32x4 t) {
        int row = mt * 16 + l15;
        int ch  = (w * 2 + nt) * 2 + (lq >> 1);
        int idx = row * HIDDEN + ((ch ^ l15) << 3) + (lq & 1) * 4;
        bf16x2 pa = {(__bf16)t[0], (__bf16)t[1]};
        bf16x2 pb = {(__bf16)t[2], (__bf16)t[3]};
        u32x2 pv;
        pv.x = __builtin_bit_cast(uint, pa);
        pv.y = __builtin_bit_cast(uint, pb);
        *(u32x2*)&zbuf[idx] = pv;
    };

    // ---- z init: z0 = F(sft=0) -> zA, single-image filter, 1 MFMA ---------
    {
        sh8 wb[2];
#pragma unroll
        for (int nt = 0; nt < 2; ++nt)
            wb[nt] = *(const sh8*)(wfB + 0 * 4096 + (w * 2 + nt) * 512 + lane * 8);
#pragma unroll
        for (int mt = 0; mt < 4; ++mt) {
            const ushort* ya = (lq < 3)
                ? &ypk[((0 * 3 + lq) * PTSB + mt * 16 + l15) * 8]
                : &zrow[0];
            sh8 yf = *(const sh8*)ya;
#pragma unroll
            for (int nt = 0; nt < 2; ++nt) {
                f32x4 t = (f32x4){0.f, 0.f, 0.f, 0.f};
                t = __builtin_amdgcn_mfma_f32_16x16x32_bf16(wb[nt], yf, t, 0, 0, 0);
                zstore4(zA, mt, nt, t);
            }
        }
    }
    __syncthreads();

    // ---- 5 layers (ONE barrier per layer; z ping-pong) ---------------------
    for (int layer = 0; layer < DEPTH; ++layer) {
        ushort* zin  = (layer & 1) ? zB : zA;
        ushort* zout = (layer & 1) ? zA : zB;

        // publish shift layer+2 into ypk buffer (layer+2)&1 (proven schedule).
        if (layer < DEPTH - 1 && w == ((layer + 2) & 3)) {
            sh8 k1;
            k1[0] = (short)(ushort)(pk1w & 0xFFFFu);
            k1[1] = (short)(ushort)(pk1w >> 16);
            k1[2] = (short)0x3F80;
            k1[3] = 0; k1[4] = 0; k1[5] = 0; k1[6] = 0; k1[7] = 0;
            ystore((layer + 2) & 1, pk0, k1, pk2);
        }

        f32x4 acc[4][2];
#pragma unroll
        for (int mt = 0; mt < 4; ++mt)
#pragma unroll
            for (int nt = 0; nt < 2; ++nt)
                acc[mt][nt] = (f32x4){0.f, 0.f, 0.f, 0.f};

        // NOT unrolled: full unroll hoists all 4 kq iterations' B-frag loads
        // which spills under the bound-4 128-reg budget (R8 lesson).
#pragma unroll 1
        for (int kq = 0; kq < 4; ++kq) {
            // single rounded-bf16 Wfwd image: [layer][kq][nt][lane][j]
            const ushort* gp = gwB + (layer * 4 + kq) * 4096 + lane * 8;
            sh8 bh0 = *(const sh8*)(gp + (w * 2 + 0) * 512);
            sh8 bh1 = *(const sh8*)(gp + (w * 2 + 1) * 512);
#pragma unroll
            for (int mt = 0; mt < 4; ++mt) {
                int row  = mt * 16 + l15;
                int base = row * HIDDEN + (((kq * 4 + lq) ^ l15) << 3);
                sh8 ah = *(const sh8*)&zin[base];
                acc[mt][0] = __builtin_amdgcn_mfma_f32_16x16x32_bf16(bh0, ah, acc[mt][0], 0, 0, 0);
                acc[mt][1] = __builtin_amdgcn_mfma_f32_16x16x32_bf16(bh1, ah, acc[mt][1], 0, 0, 0);
            }
        }
        // NO barrier here: epilogue writes zout (the OTHER buffer) — no WAR.

        // ctv: per nt, 4 consecutive cterm values at h = (w*2+nt)*16 + lq*4
        f32x4 ctv[2];
#pragma unroll
        for (int nt = 0; nt < 2; ++nt)
            ctv[nt] = *(const f32x4*)&cterm[(layer * BATCH + b) * HIDDEN
                                            + (w * 2 + nt) * 16 + lq * 4];

        // fused F phase + epilogue, per mt: z_next = (acc + ct) * F -> zout.
        // Single-image filter: ONE MFMA per (mt,nt).
        {
            sh8 wb[2];
#pragma unroll
            for (int nt = 0; nt < 2; ++nt)
                wb[nt] = *(const sh8*)(wfB + (layer + 1) * 4096
                                       + (w * 2 + nt) * 512 + lane * 8);
#pragma unroll
            for (int mt = 0; mt < 4; ++mt) {
                const ushort* ya = (lq < 3)
                    ? &ypk[((((layer + 1) & 1) * 3 + lq) * PTSB + mt * 16 + l15) * 8]
                    : &zrow[0];
                sh8 yf = *(const sh8*)ya;
#pragma unroll
                for (int nt = 0; nt < 2; ++nt) {
                    f32x4 t = (f32x4){0.f, 0.f, 0.f, 0.f};
                    t = __builtin_amdgcn_mfma_f32_16x16x32_bf16(wb[nt], yf, t, 0, 0, 0);
                    f32x4 vv;
#pragma unroll
                    for (int r = 0; r < 4; ++r)
                        vv[r] = (acc[mt][nt][r] + ctv[nt][r]) * t[r];
                    zstore4(zout, mt, nt, vv);
                }
            }
        }
        __syncthreads();   // zout visible before next layer's reads
    }

    // ---- final: out[p] = z · Wout + bout; z is in zB (layer 4 wrote it) ----
    float* psum = (float*)ypk;
    {
        int p = lane, qd = w;
        float accf = 0.0f;
#pragma unroll
        for (int cc = 0; cc < 4; ++cc) {
            int chunk = qd * 4 + cc;
            int base  = p * HIDDEN + ((chunk ^ (p & 15)) << 3);
            u32x4 hv = *(const u32x4*)&zB[base];
            uint uh[4] = {hv.x, hv.y, hv.z, hv.w};
            const float* wp = Wout + chunk * 8;
#pragma unroll
            for (int q2 = 0; q2 < 4; ++q2) {
                float a0 = __uint_as_float(uh[q2] << 16);
                float a1 = __uint_as_float(uh[q2] & 0xFFFF0000u);
                accf = fmaf(a0, wp[q2 * 2], accf);
                accf = fmaf(a1, wp[q2 * 2 + 1], accf);
            }
        }
        psum[qd * 64 + p] = accf;
    }
    __syncthreads();
    if (tid < PTSB) {
        out[p0 + tid] = boutp[0] + psum[tid] + psum[64 + tid]
                                 + psum[128 + tid] + psum[192 + tid];
    }
}

// ---------------------------------------------------------------------------
extern "C" void kernel_launch(void* const* d_in, const int* in_sizes, int n_in,
                              void* d_out, int out_size, void* d_ws, size_t ws_size,
                              hipStream_t stream) {
    (void)in_sizes; (void)n_in; (void)out_size; (void)ws_size;
    const float* x     = (const float*)d_in[0];
    const float* a     = (const float*)d_in[1];
    const float* Wftr  = (const float*)d_in[2];
    const float* bftr  = (const float*)d_in[3];
    const float* Wfwd  = (const float*)d_in[4];
    const float* bfwd  = (const float*)d_in[5];
    const float* Wcode = (const float*)d_in[6];
    const float* bcode = (const float*)d_in[7];
    const float* Wout  = (const float*)d_in[8];
    const float* bout  = (const float*)d_in[9];

    float* out   = (float*)d_out;                    // [B*N]
    float* out_x = out + NPTS;                       // [B*N*2]
    float*  cterm = (float*)d_ws;                    // 5120 floats
    ushort* wfB = (ushort*)(cterm + DEPTH * BATCH * HIDDEN);  // 24576 ushorts
    ushort* gwB = wfB + 24576;                                // 81920 ushorts

    // SH normalization coefficients on host (deterministic per call)
    CoefTab ct;
    for (int s = 0; s < 6; ++s)
        for (int yk = 0; yk < 9; ++yk) {
            int mm = yk - 4, am = mm < 0 ? -mm : mm, l = am + s;
            double ratio = 1.0;
            for (int q = l - am + 1; q <= l + am; ++q) ratio *= (double)q;
            double norm = sqrt((2.0 * l + 1.0) / (4.0 * M_PI * ratio));
            double cf = (mm == 0) ? norm : ((am & 1) ? -1.0 : 1.0) * sqrt(2.0) * norm;
            ct.c[s * 9 + yk] = (float)cf;
        }

    int nprep = DEPTH * BATCH + 96 + 320;
    sinr_prep<<<nprep, BLOCK, 0, stream>>>(a, Wcode, bcode, bfwd, Wftr, bftr,
                                           Wfwd, ct, cterm, wfB, gwB);
    sinr_main<<<NPTS / PTSB, BLOCK, 0, stream>>>(
        x, wfB, gwB, cterm, Wout, bout, out, out_x);
}